// Round 7
// baseline (6820.350 us; speedup 1.0000x reference)
//
#include <hip/hip_runtime.h>

constexpr int   T_ = 256, N_ = 64, H_ = 512;
constexpr float DT_ = 0.01f, GAMMA_ = 1.0f, EPS_ = 1.0f;

constexpr int GRID  = 256;           // 1 WG/CU
constexpr int BLOCK = 1024;          // 16 waves
constexpr int WGPN  = GRID / N_;     // 4 WGs per network
constexpr int ROWS  = H_ / WGPN;     // 128 rows per WG
constexpr int WAVES = BLOCK / 64;    // 16
constexpr int RPW   = ROWS / WAVES;  // 8 rows per wave
constexpr int LJ    = 4;             // j<LJ: W_x row in LDS; j>=LJ: registers
constexpr int SR_STRIDE = 16;        // step_ready padded to 64B lines

__device__ __forceinline__ unsigned ld_relaxed(const unsigned* p) {
    return __hip_atomic_load(p, __ATOMIC_RELAXED, __HIP_MEMORY_SCOPE_AGENT);
}

// ---------- primary path: persistent kernel, dataflow step sync ----------
// W_h: all 128 rows/WG register-resident. W_x: 64 rows LDS + 64 rows registers.
// Per-step sync: per-net arrival counters -> step_ready[t] (monotonic, no
// rendezvous, 1 fence per block per side instead of per-thread).
__global__ __launch_bounds__(BLOCK, 4)
void archetypes_persistent(const float* __restrict__ x,
                           const float* __restrict__ conn,
                           const float* __restrict__ W_h,
                           const float* __restrict__ W_x,
                           const float* __restrict__ bias,
                           const float* __restrict__ init_states,
                           float* __restrict__ out,
                           unsigned* __restrict__ step_ready,   // [(T_+1)*16]
                           unsigned* __restrict__ net_arrive)   // [(T_+1)*64]
{
    const int tid  = threadIdx.x;
    const int wg   = blockIdx.x;
    const int n    = wg / WGPN;
    const int q    = wg % WGPN;
    const int lane = tid & 63;
    const int wave = tid >> 6;

    float* states_all = out;                                   // (T+1, N, 2, H)
    float* ins_all    = out + (size_t)(T_ + 1) * N_ * 2 * H_;  // (T+1, N, H)

    __shared__ float s_wx[LJ * WAVES][H_];   // 64 W_x rows, 128 KB
    __shared__ float s_hy[H_];
    __shared__ float s_ins[H_];
    __shared__ float s_pre[ROWS];
    __shared__ float s_conn[N_];
    __shared__ float s_bias[ROWS];

    const float4* Wh4 = (const float4*)(W_h + ((size_t)n * H_ + q * ROWS) * H_);
    const float4* Wx4 = (const float4*)(W_x + ((size_t)n * H_ + q * ROWS) * H_);

    // persistent weight fragments: wave owns local rows r_l = wave + 16*j
    float4 wh_reg[RPW][2];
    float4 wx_reg[RPW - LJ][2];
    #pragma unroll
    for (int j = 0; j < RPW; ++j) {
        const int r_l = wave + WAVES * j;
        wh_reg[j][0] = Wh4[r_l * (H_ / 4) + lane];
        wh_reg[j][1] = Wh4[r_l * (H_ / 4) + 64 + lane];
    }
    #pragma unroll
    for (int j = LJ; j < RPW; ++j) {
        const int r_l = wave + WAVES * j;
        wx_reg[j - LJ][0] = Wx4[r_l * (H_ / 4) + lane];
        wx_reg[j - LJ][1] = Wx4[r_l * (H_ / 4) + 64 + lane];
    }
    {   // W_x rows [0,64) -> LDS (contiguous, coalesced)
        float4* dst = (float4*)&s_wx[0][0];
        for (int idx = tid; idx < LJ * WAVES * (H_ / 4); idx += BLOCK)
            dst[idx] = Wx4[idx];
    }
    if (tid < N_)   s_conn[tid] = conn[n * N_ + tid];
    if (tid < ROWS) s_bias[tid] = bias[n * H_ + q * ROWS + tid];

    // ---- t=0 outputs: each WG writes ITS net's slice (x4 redundant, benign)
    states_all[n * 2 * H_ + tid] = init_states[n * 2 * H_ + tid];  // 1024 elems
    if (tid < H_) ins_all[n * H_ + tid] = x[n * H_ + tid];
    __syncthreads();                        // drain stores (vmcnt0 at barrier)
    if (tid == 0) {
        __threadfence();                    // release: L2 -> coherence point
        unsigned prev = __hip_atomic_fetch_add(&net_arrive[n], 1u,
                            __ATOMIC_ACQ_REL, __HIP_MEMORY_SCOPE_AGENT);
        if (prev == WGPN - 1)
            __hip_atomic_fetch_add(&step_ready[0], 1u,
                            __ATOMIC_RELEASE, __HIP_MEMORY_SCOPE_AGENT);
    }

    const int half = tid >> 9;        // 0: conn-dot half, 1: s_hy staging half
    const int h    = tid & (H_ - 1);

    for (int t = 0; t < T_; ++t) {
        // ---- wait until all 64 nets' state t is published ----
        if (tid == 0) {
            while (ld_relaxed(&step_ready[t * SR_STRIDE]) < (unsigned)N_)
                __builtin_amdgcn_s_sleep(1);
            __threadfence();            // acquire: invalidate L1/L2
        }
        __syncthreads();

        const float* st_t = states_all + (size_t)t * N_ * 2 * H_;

        // ---- Phase A: lower 512 threads conn-dot (same sequential m-order);
        //      upper 512 stage s_hy concurrently.
        if (!half) {
            float i0 = 0.f;
            if (t > 0) {
                float a = 0.f;
                #pragma unroll 8
                for (int m = 0; m < N_; ++m)
                    a += s_conn[m] * st_t[m * 2 * H_ + h];
                i0 = a * x[(size_t)t * N_ * H_ + n * H_ + h];
            }
            s_ins[h] = i0;
            float* insd = ins_all + (size_t)(t + 1) * N_ * H_ + n * H_;
            if (h / ROWS == q) insd[h] = i0;
        } else {
            s_hy[h] = st_t[n * 2 * H_ + h];
        }
        __syncthreads();

        // ---- Phase B: pre[i] = W_h[i,:].hy + W_x[i,:].ins, 8 rows/wave ----
        {
            const float4* vh = (const float4*)s_hy;
            const float4* vi = (const float4*)s_ins;
            const float4 v0 = vh[lane], v1 = vh[64 + lane];
            const float4 u0 = vi[lane], u1 = vi[64 + lane];
            #pragma unroll
            for (int j = 0; j < RPW; ++j) {
                const int r_l = wave + WAVES * j;
                float4 wx0, wx1;
                if (j < LJ) {                  // LDS-resident W_x row
                    const float4* lx = (const float4*)&s_wx[r_l][0];
                    wx0 = lx[lane];
                    wx1 = lx[64 + lane];
                } else {                       // register-resident W_x row
                    wx0 = wx_reg[j - LJ][0];
                    wx1 = wx_reg[j - LJ][1];
                }
                float acc = 0.f;   // same per-row FP order as passing kernels
                acc += wh_reg[j][0].x * v0.x + wh_reg[j][0].y * v0.y +
                       wh_reg[j][0].z * v0.z + wh_reg[j][0].w * v0.w;
                acc += wx0.x * u0.x + wx0.y * u0.y + wx0.z * u0.z + wx0.w * u0.w;
                acc += wh_reg[j][1].x * v1.x + wh_reg[j][1].y * v1.y +
                       wh_reg[j][1].z * v1.z + wh_reg[j][1].w * v1.w;
                acc += wx1.x * u1.x + wx1.y * u1.y + wx1.z * u1.z + wx1.w * u1.w;
                #pragma unroll
                for (int off = 32; off; off >>= 1)
                    acc += __shfl_xor(acc, off);
                if (lane == 0) s_pre[r_l] = acc;
            }
        }
        __syncthreads();

        // ---- Phase C: state update for this WG's 128 rows ----
        if (tid < ROWS) {
            const int i    = q * ROWS + tid;
            const float pre  = s_pre[tid] + s_bias[tid];
            const float hy   = s_hy[i];
            const float hz   = st_t[n * 2 * H_ + H_ + i];
            const float th   = tanhf(pre);
            const float hz_n = hz + DT_ * (th - GAMMA_ * hy - EPS_ * hz);
            const float hy_n = hy + DT_ * hz_n;
            float* st1 = states_all + (size_t)(t + 1) * N_ * 2 * H_ + n * 2 * H_;
            st1[i]      = hy_n;
            st1[H_ + i] = hz_n;
        }
        __syncthreads();                    // drain phase-C stores to L2
        if (tid == 0) {
            __threadfence();                // release: publish state t+1
            unsigned prev = __hip_atomic_fetch_add(&net_arrive[(t + 1) * N_ + n],
                                1u, __ATOMIC_ACQ_REL, __HIP_MEMORY_SCOPE_AGENT);
            if (prev == WGPN - 1)
                __hip_atomic_fetch_add(&step_ready[(t + 1) * SR_STRIDE], 1u,
                                __ATOMIC_RELEASE, __HIP_MEMORY_SCOPE_AGENT);
        }
    }
}

// ---------- fallback path: per-step kernels, stream-ordered ----------
constexpr int FGRID = 1024, FBLOCK = 256, FWGPN = 16, FROWS = 32, FRPW = 8;

__global__ __launch_bounds__(FBLOCK)
void archetypes_init(const float* __restrict__ x,
                     const float* __restrict__ init_states,
                     float* __restrict__ out)
{
    float* states_all = out;
    float* ins_all    = out + (size_t)(T_ + 1) * N_ * 2 * H_;
    const int idx = blockIdx.x * FBLOCK + threadIdx.x;
    if (idx < N_ * 2 * H_) states_all[idx] = init_states[idx];
    if (idx < N_ * H_)     ins_all[idx]    = x[idx];
}

__global__ __launch_bounds__(FBLOCK)
void archetypes_step(int t,
                     const float* __restrict__ x,
                     const float* __restrict__ conn,
                     const float* __restrict__ W_h,
                     const float* __restrict__ W_x,
                     const float* __restrict__ bias,
                     float* __restrict__ out)
{
    const int tid  = threadIdx.x;
    const int wg   = blockIdx.x;
    const int n    = wg / FWGPN;
    const int q    = wg % FWGPN;
    const int lane = tid & 63;
    const int wave = tid >> 6;

    float* states_all = out;
    float* ins_all    = out + (size_t)(T_ + 1) * N_ * 2 * H_;

    __shared__ float s_hy[H_];
    __shared__ float s_ins[H_];
    __shared__ float s_pre[FROWS];
    __shared__ float s_conn[N_];
    __shared__ float s_bias[FROWS];

    if (tid < N_)    s_conn[tid] = conn[n * N_ + tid];
    if (tid < FROWS) s_bias[tid] = bias[n * H_ + q * FROWS + tid];
    __syncthreads();

    const float* st_t = states_all + (size_t)t * N_ * 2 * H_;
    {
        const int h0 = tid, h1 = tid + 256;
        float i0 = 0.f, i1 = 0.f;
        if (t > 0) {
            const float* xr = x + (size_t)t * N_ * H_ + n * H_;
            float a0 = 0.f, a1 = 0.f;
            #pragma unroll 8
            for (int m = 0; m < N_; ++m) {
                const float c = s_conn[m];
                a0 += c * st_t[m * 2 * H_ + h0];
                a1 += c * st_t[m * 2 * H_ + h1];
            }
            i0 = a0 * xr[h0];
            i1 = a1 * xr[h1];
        }
        s_ins[h0] = i0;
        s_ins[h1] = i1;
        s_hy[h0] = st_t[n * 2 * H_ + h0];
        s_hy[h1] = st_t[n * 2 * H_ + h1];
        float* insd = ins_all + (size_t)(t + 1) * N_ * H_ + n * H_;
        if (h0 / FROWS == q) insd[h0] = i0;
        if (h1 / FROWS == q) insd[h1] = i1;
    }
    __syncthreads();
    {
        const float4* vh = (const float4*)s_hy;
        const float4* vi = (const float4*)s_ins;
        const float4* Wh4 = (const float4*)(W_h + ((size_t)n * H_ + q * FROWS) * H_);
        const float4* Wx4 = (const float4*)(W_x + ((size_t)n * H_ + q * FROWS) * H_);
        const float4 v0 = vh[lane], v1 = vh[64 + lane];
        const float4 u0 = vi[lane], u1 = vi[64 + lane];
        #pragma unroll
        for (int j = 0; j < FRPW; ++j) {
            const int r_l = wave + 4 * j;
            const float4 a0 = Wh4[r_l * (H_ / 4) + lane];
            const float4 a1 = Wh4[r_l * (H_ / 4) + 64 + lane];
            const float4 wx0 = Wx4[r_l * (H_ / 4) + lane];
            const float4 wx1 = Wx4[r_l * (H_ / 4) + 64 + lane];
            float acc = 0.f;
            acc += a0.x * v0.x + a0.y * v0.y + a0.z * v0.z + a0.w * v0.w;
            acc += wx0.x * u0.x + wx0.y * u0.y + wx0.z * u0.z + wx0.w * u0.w;
            acc += a1.x * v1.x + a1.y * v1.y + a1.z * v1.z + a1.w * v1.w;
            acc += wx1.x * u1.x + wx1.y * u1.y + wx1.z * u1.z + wx1.w * u1.w;
            #pragma unroll
            for (int off = 32; off; off >>= 1)
                acc += __shfl_xor(acc, off);
            if (lane == 0) s_pre[r_l] = acc;
        }
    }
    __syncthreads();
    if (tid < FROWS) {
        const int i   = q * FROWS + tid;
        const float pre  = s_pre[tid] + s_bias[tid];
        const float hy   = st_t[n * 2 * H_ + i];
        const float hz   = st_t[n * 2 * H_ + H_ + i];
        const float th   = tanhf(pre);
        const float hz_n = hz + DT_ * (th - GAMMA_ * hy - EPS_ * hz);
        const float hy_n = hy + DT_ * hz_n;
        float* st1 = states_all + (size_t)(t + 1) * N_ * 2 * H_ + n * 2 * H_;
        st1[i]      = hy_n;
        st1[H_ + i] = hz_n;
    }
}

extern "C" void kernel_launch(void* const* d_in, const int* in_sizes, int n_in,
                              void* d_out, int out_size, void* d_ws, size_t ws_size,
                              hipStream_t stream) {
    const float* x     = (const float*)d_in[0];
    const float* conn  = (const float*)d_in[1];
    const float* W_h   = (const float*)d_in[2];
    const float* W_x   = (const float*)d_in[3];
    const float* bias  = (const float*)d_in[4];
    const float* inits = (const float*)d_in[5];
    float*       outp  = (float*)d_out;

    unsigned* step_ready = (unsigned*)d_ws;                       // (T_+1)*16
    unsigned* net_arrive = step_ready + (size_t)(T_ + 1) * SR_STRIDE;
    const size_t flag_bytes =
        sizeof(unsigned) * ((size_t)(T_ + 1) * SR_STRIDE + (size_t)(T_ + 1) * N_);

    // Capture-safe, deterministic host-side gate: cooperative path only if all
    // GRID WGs are provably co-resident and the workspace fits the flags.
    int perCU = 0;
    (void)hipOccupancyMaxActiveBlocksPerMultiprocessor(
        &perCU, (const void*)archetypes_persistent, BLOCK, 0);
    const bool coop_ok = (perCU * 256 >= GRID) && (ws_size >= flag_bytes);

    if (coop_ok) {
        hipMemsetAsync(d_ws, 0, flag_bytes, stream);   // flags are 0xAA-poisoned
        void* args[] = {(void*)&x, (void*)&conn, (void*)&W_h, (void*)&W_x,
                        (void*)&bias, (void*)&inits, (void*)&outp,
                        (void*)&step_ready, (void*)&net_arrive};
        hipLaunchCooperativeKernel((void*)archetypes_persistent,
                                   dim3(GRID), dim3(BLOCK), args, 0, stream);
    } else {
        archetypes_init<<<dim3((N_ * 2 * H_ + FBLOCK - 1) / FBLOCK), dim3(FBLOCK),
                          0, stream>>>(x, inits, outp);
        for (int t = 0; t < T_; ++t)
            archetypes_step<<<dim3(FGRID), dim3(FBLOCK), 0, stream>>>(
                t, x, conn, W_h, W_x, bias, outp);
    }
}

// Round 10
// 6621.004 us; speedup vs baseline: 1.0301x; 1.0301x over previous
//
#include <hip/hip_runtime.h>

constexpr int   T_ = 256, N_ = 64, H_ = 512;
constexpr float DT_ = 0.01f, GAMMA_ = 1.0f, EPS_ = 1.0f;

constexpr int GRID  = 256;           // 1 WG/CU
constexpr int BLOCK = 1024;          // 16 waves
constexpr int WGPN  = GRID / N_;     // 4 WGs per network
constexpr int ROWS  = H_ / WGPN;     // 128 rows per WG
constexpr int WAVES = BLOCK / 64;    // 16
constexpr int RPW   = ROWS / WAVES;  // 8 rows per wave
constexpr int LJ    = 4;             // j<LJ: W_x row in LDS; j>=LJ: registers
constexpr int SPIN_CAP = 200000;     // liveness guard: ~10ms max per wait

// Agent-scope (device) relaxed atomics: single sc1 memory ops coherent at the
// point-of-coherence. NO fences anywhere in the loop -> no buffer_wbl2 /
// buffer_inv L2 cache-walks per step (the invariant ~20us/step cost that
// survived three sync-protocol redesigns).
__device__ __forceinline__ float ld_agent_f(const float* p) {
    return __hip_atomic_load(p, __ATOMIC_RELAXED, __HIP_MEMORY_SCOPE_AGENT);
}
__device__ __forceinline__ void st_agent_f(float* p, float v) {
    __hip_atomic_store(p, v, __ATOMIC_RELAXED, __HIP_MEMORY_SCOPE_AGENT);
}
__device__ __forceinline__ unsigned ld_agent_u(const unsigned* p) {
    return __hip_atomic_load(p, __ATOMIC_RELAXED, __HIP_MEMORY_SCOPE_AGENT);
}

// ---------- primary path: persistent kernel, fence-free dataflow ----------
// Cross-XCD data = hy ring (2 x 64 x 512 f32 in d_ws, sc1 ops) + per-net
// arrival flags. hz: thread-private register. Output history: normal cached
// stores (published once by end-of-kernel release).
//
// Ring-slot safety: a WG can only overwrite slot t&1 (as slot (t+2)&1) during
// step t+1, which requires arrive[t+1] full, which requires every WG past its
// step-t Phase C -- long after all Phase-A reads of slot t&1 completed.
// Store->flag ordering: __syncthreads() emits s_waitcnt vmcnt(0), draining
// the sc1 ring stores (ack'd at the coherence point) before the flag RMW.
// Liveness guard: all spins are bounded; a protocol stall surfaces as a
// wrong answer (diagnosable) instead of a wedged GPU.
__global__ __launch_bounds__(BLOCK, 4)
void archetypes_persistent(const float* __restrict__ x,
                           const float* __restrict__ conn,
                           const float* __restrict__ W_h,
                           const float* __restrict__ W_x,
                           const float* __restrict__ bias,
                           const float* __restrict__ init_states,
                           float* __restrict__ out,
                           float* __restrict__ ring,      // [2][N_*H_]
                           unsigned* __restrict__ arrive) // [(T_+1)*N_]
{
    const int tid  = threadIdx.x;
    const int wg   = blockIdx.x;
    const int n    = wg / WGPN;
    const int q    = wg % WGPN;
    const int lane = tid & 63;
    const int wave = tid >> 6;

    float* states_all = out;                                   // (T+1, N, 2, H)
    float* ins_all    = out + (size_t)(T_ + 1) * N_ * 2 * H_;  // (T+1, N, H)

    __shared__ float s_wx[LJ * WAVES][H_];   // 64 W_x rows, 128 KB
    __shared__ float s_hy[H_];
    __shared__ float s_ins[H_];
    __shared__ float s_pre[ROWS];
    __shared__ float s_conn[N_];
    __shared__ float s_bias[ROWS];

    const float4* Wh4 = (const float4*)(W_h + ((size_t)n * H_ + q * ROWS) * H_);
    const float4* Wx4 = (const float4*)(W_x + ((size_t)n * H_ + q * ROWS) * H_);

    // persistent weight fragments: wave owns local rows r_l = wave + 16*j
    float4 wh_reg[RPW][2];
    float4 wx_reg[RPW - LJ][2];
    #pragma unroll
    for (int j = 0; j < RPW; ++j) {
        const int r_l = wave + WAVES * j;
        wh_reg[j][0] = Wh4[r_l * (H_ / 4) + lane];
        wh_reg[j][1] = Wh4[r_l * (H_ / 4) + 64 + lane];
    }
    #pragma unroll
    for (int j = LJ; j < RPW; ++j) {
        const int r_l = wave + WAVES * j;
        wx_reg[j - LJ][0] = Wx4[r_l * (H_ / 4) + lane];
        wx_reg[j - LJ][1] = Wx4[r_l * (H_ / 4) + 64 + lane];
    }
    {   // W_x rows [0,64) -> LDS (contiguous, coalesced)
        float4* dst = (float4*)&s_wx[0][0];
        for (int idx = tid; idx < LJ * WAVES * (H_ / 4); idx += BLOCK)
            dst[idx] = Wx4[idx];
    }
    if (tid < N_)   s_conn[tid] = conn[n * N_ + tid];
    if (tid < ROWS) s_bias[tid] = bias[n * H_ + q * ROWS + tid];

    // hz lives in a register for the WG's 128 rows (never leaves the WG)
    float hz_reg = 0.f;
    if (tid < ROWS) hz_reg = init_states[n * 2 * H_ + H_ + q * ROWS + tid];

    // ---- t=0 outputs: own net's slice (x4 redundant, benign), cached stores
    states_all[n * 2 * H_ + tid] = init_states[n * 2 * H_ + tid];
    if (tid < H_) ins_all[n * H_ + tid] = x[n * H_ + tid];
    // No publication needed for t=0: Phase A at t=0 reads nothing cross-WG.

    const int half = tid >> 9;        // 0: conn-dot half, 1: s_hy staging half
    const int h    = tid & (H_ - 1);

    for (int t = 0; t < T_; ++t) {
        // ---- wait (t>0): all 64 nets' hy(t) published in ring[t&1].
        //      64 parallel per-net flag lines, polled by the first wave.
        //      Bounded spin: stall -> wrong answer, never a wedged GPU.
        if (t > 0 && tid < N_) {
            const unsigned* a = arrive + (size_t)t * N_ + tid;
            int guard = 0;
            while (ld_agent_u(a) < (unsigned)WGPN && ++guard < SPIN_CAP)
                __builtin_amdgcn_s_sleep(2);
        }
        __syncthreads();   // also covers LDS staging before first use (t=0)

        const float* rg = ring + (size_t)(t & 1) * N_ * H_;

        // ---- Phase A: lower 512 threads conn-dot (same sequential m-order,
        //      hand-batched 8 loads/iter for MLP with sc1 loads); upper 512
        //      stage s_hy concurrently.
        if (!half) {
            float i0 = 0.f;
            if (t > 0) {
                float a = 0.f;
                for (int m0 = 0; m0 < N_; m0 += 8) {
                    float v0 = ld_agent_f(rg + (m0 + 0) * H_ + h);
                    float v1 = ld_agent_f(rg + (m0 + 1) * H_ + h);
                    float v2 = ld_agent_f(rg + (m0 + 2) * H_ + h);
                    float v3 = ld_agent_f(rg + (m0 + 3) * H_ + h);
                    float v4 = ld_agent_f(rg + (m0 + 4) * H_ + h);
                    float v5 = ld_agent_f(rg + (m0 + 5) * H_ + h);
                    float v6 = ld_agent_f(rg + (m0 + 6) * H_ + h);
                    float v7 = ld_agent_f(rg + (m0 + 7) * H_ + h);
                    a += s_conn[m0 + 0] * v0;   // FP order = prior kernels
                    a += s_conn[m0 + 1] * v1;
                    a += s_conn[m0 + 2] * v2;
                    a += s_conn[m0 + 3] * v3;
                    a += s_conn[m0 + 4] * v4;
                    a += s_conn[m0 + 5] * v5;
                    a += s_conn[m0 + 6] * v6;
                    a += s_conn[m0 + 7] * v7;
                }
                i0 = a * x[(size_t)t * N_ * H_ + n * H_ + h];
            }
            s_ins[h] = i0;
            float* insd = ins_all + (size_t)(t + 1) * N_ * H_ + n * H_;
            if (h / ROWS == q) insd[h] = i0;    // cached output store
        } else {
            s_hy[h] = (t == 0) ? init_states[n * 2 * H_ + h]
                               : ld_agent_f(rg + n * H_ + h);
        }
        __syncthreads();

        // ---- Phase B: pre[i] = W_h[i,:].hy + W_x[i,:].ins, 8 rows/wave ----
        {
            const float4* vh = (const float4*)s_hy;
            const float4* vi = (const float4*)s_ins;
            const float4 v0 = vh[lane], v1 = vh[64 + lane];
            const float4 u0 = vi[lane], u1 = vi[64 + lane];
            #pragma unroll
            for (int j = 0; j < RPW; ++j) {
                const int r_l = wave + WAVES * j;
                float4 wx0, wx1;
                if (j < LJ) {                  // LDS-resident W_x row
                    const float4* lx = (const float4*)&s_wx[r_l][0];
                    wx0 = lx[lane];
                    wx1 = lx[64 + lane];
                } else {                       // register-resident W_x row
                    wx0 = wx_reg[j - LJ][0];
                    wx1 = wx_reg[j - LJ][1];
                }
                float acc = 0.f;   // same per-row FP order as passing kernels
                acc += wh_reg[j][0].x * v0.x + wh_reg[j][0].y * v0.y +
                       wh_reg[j][0].z * v0.z + wh_reg[j][0].w * v0.w;
                acc += wx0.x * u0.x + wx0.y * u0.y + wx0.z * u0.z + wx0.w * u0.w;
                acc += wh_reg[j][1].x * v1.x + wh_reg[j][1].y * v1.y +
                       wh_reg[j][1].z * v1.z + wh_reg[j][1].w * v1.w;
                acc += wx1.x * u1.x + wx1.y * u1.y + wx1.z * u1.z + wx1.w * u1.w;
                #pragma unroll
                for (int off = 32; off; off >>= 1)
                    acc += __shfl_xor(acc, off);
                if (lane == 0) s_pre[r_l] = acc;
            }
        }
        __syncthreads();

        // ---- Phase C: state update for this WG's 128 rows ----
        if (tid < ROWS) {
            const int i    = q * ROWS + tid;
            const float pre  = s_pre[tid] + s_bias[tid];
            const float hy   = s_hy[i];
            const float hz   = hz_reg;
            const float th   = tanhf(pre);
            const float hz_n = hz + DT_ * (th - GAMMA_ * hy - EPS_ * hz);
            const float hy_n = hy + DT_ * hz_n;
            hz_reg = hz_n;
            float* st1 = states_all + (size_t)(t + 1) * N_ * 2 * H_ + n * 2 * H_;
            st1[i]      = hy_n;                 // cached output stores
            st1[H_ + i] = hz_n;
            st_agent_f(ring + (size_t)((t + 1) & 1) * N_ * H_ + n * H_ + i,
                       hy_n);                   // publish hy (sc1, no fence)
        }
        __syncthreads();   // vmcnt(0) drain: ring stores ack'd at coherence pt
        if (tid == 0)
            __hip_atomic_fetch_add(&arrive[(size_t)(t + 1) * N_ + n], 1u,
                                   __ATOMIC_RELAXED, __HIP_MEMORY_SCOPE_AGENT);
    }
}

// ---------- fallback path: per-step kernels, stream-ordered ----------
constexpr int FGRID = 1024, FBLOCK = 256, FWGPN = 16, FROWS = 32, FRPW = 8;

__global__ __launch_bounds__(FBLOCK)
void archetypes_init(const float* __restrict__ x,
                     const float* __restrict__ init_states,
                     float* __restrict__ out)
{
    float* states_all = out;
    float* ins_all    = out + (size_t)(T_ + 1) * N_ * 2 * H_;
    const int idx = blockIdx.x * FBLOCK + threadIdx.x;
    if (idx < N_ * 2 * H_) states_all[idx] = init_states[idx];
    if (idx < N_ * H_)     ins_all[idx]    = x[idx];
}

__global__ __launch_bounds__(FBLOCK)
void archetypes_step(int t,
                     const float* __restrict__ x,
                     const float* __restrict__ conn,
                     const float* __restrict__ W_h,
                     const float* __restrict__ W_x,
                     const float* __restrict__ bias,
                     float* __restrict__ out)
{
    const int tid  = threadIdx.x;
    const int wg   = blockIdx.x;
    const int n    = wg / FWGPN;
    const int q    = wg % FWGPN;
    const int lane = tid & 63;
    const int wave = tid >> 6;

    float* states_all = out;
    float* ins_all    = out + (size_t)(T_ + 1) * N_ * 2 * H_;

    __shared__ float s_hy[H_];
    __shared__ float s_ins[H_];
    __shared__ float s_pre[FROWS];
    __shared__ float s_conn[N_];
    __shared__ float s_bias[FROWS];

    if (tid < N_)    s_conn[tid] = conn[n * N_ + tid];
    if (tid < FROWS) s_bias[tid] = bias[n * H_ + q * FROWS + tid];
    __syncthreads();

    const float* st_t = states_all + (size_t)t * N_ * 2 * H_;
    {
        const int h0 = tid, h1 = tid + 256;
        float i0 = 0.f, i1 = 0.f;
        if (t > 0) {
            const float* xr = x + (size_t)t * N_ * H_ + n * H_;
            float a0 = 0.f, a1 = 0.f;
            #pragma unroll 8
            for (int m = 0; m < N_; ++m) {
                const float c = s_conn[m];
                a0 += c * st_t[m * 2 * H_ + h0];
                a1 += c * st_t[m * 2 * H_ + h1];
            }
            i0 = a0 * xr[h0];
            i1 = a1 * xr[h1];
        }
        s_ins[h0] = i0;
        s_ins[h1] = i1;
        s_hy[h0] = st_t[n * 2 * H_ + h0];
        s_hy[h1] = st_t[n * 2 * H_ + h1];
        float* insd = ins_all + (size_t)(t + 1) * N_ * H_ + n * H_;
        if (h0 / FROWS == q) insd[h0] = i0;
        if (h1 / FROWS == q) insd[h1] = i1;
    }
    __syncthreads();
    {
        const float4* vh = (const float4*)s_hy;
        const float4* vi = (const float4*)s_ins;
        const float4* Wh4 = (const float4*)(W_h + ((size_t)n * H_ + q * FROWS) * H_);
        const float4* Wx4 = (const float4*)(W_x + ((size_t)n * H_ + q * FROWS) * H_);
        const float4 v0 = vh[lane], v1 = vh[64 + lane];
        const float4 u0 = vi[lane], u1 = vi[64 + lane];
        #pragma unroll
        for (int j = 0; j < FRPW; ++j) {
            const int r_l = wave + 4 * j;
            const float4 a0 = Wh4[r_l * (H_ / 4) + lane];
            const float4 a1 = Wh4[r_l * (H_ / 4) + 64 + lane];
            const float4 wx0 = Wx4[r_l * (H_ / 4) + lane];
            const float4 wx1 = Wx4[r_l * (H_ / 4) + 64 + lane];
            float acc = 0.f;
            acc += a0.x * v0.x + a0.y * v0.y + a0.z * v0.z + a0.w * v0.w;
            acc += wx0.x * u0.x + wx0.y * u0.y + wx0.z * u0.z + wx0.w * u0.w;
            acc += a1.x * v1.x + a1.y * v1.y + a1.z * v1.z + a1.w * v1.w;
            acc += wx1.x * u1.x + wx1.y * u1.y + wx1.z * u1.z + wx1.w * u1.w;
            #pragma unroll
            for (int off = 32; off; off >>= 1)
                acc += __shfl_xor(acc, off);
            if (lane == 0) s_pre[r_l] = acc;
        }
    }
    __syncthreads();
    if (tid < FROWS) {
        const int i   = q * FROWS + tid;
        const float pre  = s_pre[tid] + s_bias[tid];
        const float hy   = st_t[n * 2 * H_ + i];
        const float hz   = st_t[n * 2 * H_ + H_ + i];
        const float th   = tanhf(pre);
        const float hz_n = hz + DT_ * (th - GAMMA_ * hy - EPS_ * hz);
        const float hy_n = hy + DT_ * hz_n;
        float* st1 = states_all + (size_t)(t + 1) * N_ * 2 * H_ + n * 2 * H_;
        st1[i]      = hy_n;
        st1[H_ + i] = hz_n;
    }
}

extern "C" void kernel_launch(void* const* d_in, const int* in_sizes, int n_in,
                              void* d_out, int out_size, void* d_ws, size_t ws_size,
                              hipStream_t stream) {
    const float* x     = (const float*)d_in[0];
    const float* conn  = (const float*)d_in[1];
    const float* W_h   = (const float*)d_in[2];
    const float* W_x   = (const float*)d_in[3];
    const float* bias  = (const float*)d_in[4];
    const float* inits = (const float*)d_in[5];
    float*       outp  = (float*)d_out;

    float*    ring        = (float*)d_ws;                    // 2*N_*H_ floats
    unsigned* arrive      = (unsigned*)(ring + 2 * N_ * H_); // (T_+1)*N_ u32
    const size_t ring_bytes   = sizeof(float) * 2 * N_ * H_;
    const size_t arrive_bytes = sizeof(unsigned) * (size_t)(T_ + 1) * N_;

    // Capture-safe, deterministic host-side gate.
    int perCU = 0;
    (void)hipOccupancyMaxActiveBlocksPerMultiprocessor(
        &perCU, (const void*)archetypes_persistent, BLOCK, 0);
    const bool coop_ok =
        (perCU * 256 >= GRID) && (ws_size >= ring_bytes + arrive_bytes);

    if (coop_ok) {
        // flags must start at 0 (d_ws is 0xAA-poisoned); ring needs no init
        // (every slot is written before it is read).
        hipMemsetAsync(arrive, 0, arrive_bytes, stream);
        void* args[] = {(void*)&x, (void*)&conn, (void*)&W_h, (void*)&W_x,
                        (void*)&bias, (void*)&inits, (void*)&outp,
                        (void*)&ring, (void*)&arrive};
        hipLaunchCooperativeKernel((void*)archetypes_persistent,
                                   dim3(GRID), dim3(BLOCK), args, 0, stream);
    } else {
        archetypes_init<<<dim3((N_ * 2 * H_ + FBLOCK - 1) / FBLOCK), dim3(FBLOCK),
                          0, stream>>>(x, inits, outp);
        for (int t = 0; t < T_; ++t)
            archetypes_step<<<dim3(FGRID), dim3(FBLOCK), 0, stream>>>(
                t, x, conn, W_h, W_x, bias, outp);
    }
}